// Round 13
// baseline (199.489 us; speedup 1.0000x reference)
//
#include <hip/hip_runtime.h>
#include <hip/hip_fp16.h>
#include <math.h>

// ---------------------------------------------------------------------------
// SSHConv3D fused, round 13: r11 structure (8x4x4 tile, 4-way harmonic split,
// 512-thread blocks) + ANTIPODAL PARITY FOLDING of the conv:
//   a[-off] = (-1)^n a[+off]  (Y_n parity; even radial profile), so
//   z = sum_pairs a[+off] * (x[p+off] +/- x[p-off])
// halves conv hfma2 (92 entries -> 46 pairs). Groups reorganized so every
// conv pass is parity-uniform: g0={h13,h14}(n3,-), g1={h15+h12}(n3,-)+{h0}(n0,+),
// g2={h7,h8}(n2,+), g3={h3+h2}(n1,-)+{h6}(n2,+).
//
// ws layout (bytes):
//   [0,     11776) patab : h2[16 h][46 pair][4] = {(ar0),(ai0),(ar1),(ai1)} repl.
//   [23552, 31744) wT2   : h2[n][f][j][8 cp]
//   [31744, 32768) cw2   : h2[f][8 cp]
//   [32768, 49152) pwT   : f32[(f*4+n)][fo]
//   [49152, 49280) obase : f32[32]
//   [49280, 49464) edp   : int[46] byte offset of +off (pre-scaled by 48)
//   [49464, 49648) edm   : int[46] byte offset of -off
// Pair segments: [0,3)=j0-only, [3,13)=both j, [13,46)=j1-only.
// ---------------------------------------------------------------------------

#define TX 8
#define TY 4
#define TZ 4
#define LXX 12
#define LYY 8
#define LZZ 8
#define NPOS 768
#define CPAD 24
#define POSB 48

#define PAT_B   0
#define WT2_B   23552
#define CW2_B   31744
#define PWT_B   32768
#define OB_B    49152
#define ED_B    49280

typedef __half2 h2;
union I4H { int4 v; h2 h[4]; };

__global__ __launch_bounds__(256) void ssh_init(
    const float* __restrict__ w, const float* __restrict__ cw,
    const float* __restrict__ proj_w, const float* __restrict__ spec_bias,
    const float* __restrict__ proj_b, char* __restrict__ wsb)
{
    __shared__ float shr[125][16];
    __shared__ float shi[125][16];
    __shared__ float prof[125][2];
    __shared__ float norms[2][16];
    __shared__ int pepos[46];
    const int tid = threadIdx.x;
    const float fourpi = 4.0f * 3.14159265358979323846f;

    for (int p = tid; p < 125; p += 256) {
        int d2 = p % 5, d1 = (p / 5) % 5, d0 = p / 25;
        float xc = (float)(d1 - 2), yc = (float)(d0 - 2), zc = (float)(d2 - 2);
        float r2 = xc*xc + yc*yc + zc*zc;
        float r  = sqrtf(r2);
        float phi = atan2f(yc, xc);
        float ct = (r > 0.f) ? (zc / r) : 0.f;
        float st = sqrtf(fmaxf(0.f, 1.f - ct*ct));
        float c1 = cosf(phi), s1 = sinf(phi);
        float c2 = c1*c1 - s1*s1, s2 = 2.f*s1*c1;
        float c3 = c2*c1 - s2*s1, s3 = s2*c1 + c2*s1;
        float P10 = ct,              P11 = -st;
        float P20 = 0.5f*(3.f*ct*ct - 1.f), P21 = -3.f*ct*st, P22 = 3.f*st*st;
        float P30 = 0.5f*(5.f*ct*ct*ct - 3.f*ct);
        float P31 = -1.5f*(5.f*ct*ct - 1.f)*st;
        float P32 = 15.f*ct*st*st;
        float P33 = -15.f*st*st*st;
        float N00 = sqrtf(1.f/fourpi);
        float N10 = sqrtf(3.f/fourpi);
        float N11 = sqrtf(3.f/fourpi * 0.5f);
        float N20 = sqrtf(5.f/fourpi);
        float N21 = sqrtf(5.f/fourpi / 6.f);
        float N22 = sqrtf(5.f/fourpi / 24.f);
        float N30 = sqrtf(7.f/fourpi);
        float N31 = sqrtf(7.f/fourpi / 12.f);
        float N32 = sqrtf(7.f/fourpi / 120.f);
        float N33 = sqrtf(7.f/fourpi / 720.f);
        float b;
        shr[p][0] = N00;               shi[p][0] = 0.f;
        shr[p][2] = N10*P10;           shi[p][2] = 0.f;
        b = N11*P11;
        shr[p][3] =  b*c1;             shi[p][3] =  b*s1;
        shr[p][1] = -b*c1;             shi[p][1] =  b*s1;
        shr[p][6] = N20*P20;           shi[p][6] = 0.f;
        b = N21*P21;
        shr[p][7] =  b*c1;             shi[p][7] =  b*s1;
        shr[p][5] = -b*c1;             shi[p][5] =  b*s1;
        b = N22*P22;
        shr[p][8] =  b*c2;             shi[p][8] =  b*s2;
        shr[p][4] =  b*c2;             shi[p][4] = -b*s2;
        shr[p][12] = N30*P30;          shi[p][12] = 0.f;
        b = N31*P31;
        shr[p][13] =  b*c1;            shi[p][13] =  b*s1;
        shr[p][11] = -b*c1;            shi[p][11] =  b*s1;
        b = N32*P32;
        shr[p][14] =  b*c2;            shi[p][14] =  b*s2;
        shr[p][10] =  b*c2;            shi[p][10] = -b*s2;
        b = N33*P33;
        shr[p][15] =  b*c3;            shi[p][15] =  b*s3;
        shr[p][9]  = -b*c3;            shi[p][9]  =  b*s3;
        prof[p][0] = fmaxf(0.f, 1.f - fabsf(r - 1.f));
        prof[p][1] = fmaxf(0.f, 1.f - fabsf(r - 2.f));
    }
    __syncthreads();

    if (tid < 32) {
        int j = tid >> 4, h = tid & 15;
        float acc = 0.f;
        for (int p = 0; p < 125; ++p) {
            float pr = prof[p][j];
            acc += pr*pr*(shr[p][h]*shr[p][h] + shi[p][h]*shi[p][h]);
        }
        float nn = sqrtf(acc);
        norms[j][h] = (nn > 0.f) ? nn : 1.f;
    }
    // pair-rank computation: representative p < 62 (antipode 124-p), same class.
    // pair segment bases: cls0 -> 0 (3 pairs), cls1 -> 3 (10), cls2 -> 13 (33).
    if (tid < 62) {
        int p = tid;
        int d2 = p % 5, d1 = (p / 5) % 5, d0 = p / 25;
        int ix = d1 - 2, iy = d0 - 2, iz = d2 - 2;
        int r2i = ix*ix + iy*iy + iz*iz;
        int cls = (r2i == 1) ? 0 : (r2i == 2 || r2i == 3) ? 1
                : (r2i == 4 || r2i == 5 || r2i == 6 || r2i == 8) ? 2 : -1;
        if (cls >= 0) {
            int rank = (cls == 0) ? 0 : (cls == 1) ? 3 : 13;
            for (int q = 0; q < p; ++q) {
                int e2 = q % 5, e1 = (q / 5) % 5, e0 = q / 25;
                int jx = e1 - 2, jy = e0 - 2, jz = e2 - 2;
                int s2i = jx*jx + jy*jy + jz*jz;
                int c2i = (s2i == 1) ? 0 : (s2i == 2 || s2i == 3) ? 1
                       : (s2i == 4 || s2i == 5 || s2i == 6 || s2i == 8) ? 2 : -1;
                rank += (c2i == cls) ? 1 : 0;   // all q<62 reps counted (q<p<62)
            }
            pepos[rank] = p;
            ((int*)(wsb + ED_B))[rank]      = (d0*(LYY*LXX) + d1*LXX + d2) * POSB;
            ((int*)(wsb + ED_B))[46 + rank] = ((4-d0)*(LYY*LXX) + (4-d1)*LXX + (4-d2)) * POSB;
        }
    }
    __syncthreads();

    // patab: coefficient of the + (representative) offset per pair
    h2* pat = (h2*)(wsb + PAT_B);
    for (int t = tid; t < 46*16; t += 256) {
        int h = t / 46, k = t - h*46;
        int p = pepos[k];
        float c0 = prof[p][0] / norms[0][h];
        float c1v = prof[p][1] / norms[1][h];
        pat[(h*46+k)*4 + 0] = __float2half2_rn(c0*shr[p][h]);
        pat[(h*46+k)*4 + 1] = __float2half2_rn(c0*shi[p][h]);
        pat[(h*46+k)*4 + 2] = __float2half2_rn(c1v*shr[p][h]);
        pat[(h*46+k)*4 + 3] = __float2half2_rn(c1v*shi[p][h]);
    }
    // wT2: h2 index = n*512 + f*16 + j*8 + cp
    h2* wt2h = (h2*)(wsb + WT2_B);
    for (int t = tid; t < 2048; t += 256) {
        int n = t >> 9, f = (t >> 4) & 31, j = (t >> 3) & 1, cp = t & 7;
        float a = w[((2*cp*32 + f)*2 + j)*4 + n];
        float b = w[(((2*cp+1)*32 + f)*2 + j)*4 + n];
        wt2h[t] = __halves2half2(__float2half(a), __float2half(b));
    }
    // cw2: h2 index = f*8 + cp
    h2* cw2h = (h2*)(wsb + CW2_B);
    for (int t = tid; t < 256; t += 256) {
        int f = t >> 3, cp = t & 7;
        cw2h[t] = __halves2half2(__float2half(cw[f*16 + 2*cp]),
                                 __float2half(cw[f*16 + 2*cp + 1]));
    }
    // pwT f32 [(f*4+n)][fo]
    float* pwT = (float*)(wsb + PWT_B);
    for (int t = tid; t < 4096; t += 256) {
        int i = t >> 5, fo = t & 31;
        pwT[t] = proj_w[fo*128 + i];
    }
    if (tid < 32) {
        float acc = proj_b[tid];
        for (int i = 0; i < 128; ++i) acc += proj_w[tid*128 + i] * spec_bias[i];
        ((float*)(wsb + OB_B))[tid] = acc;
    }
}

// ---- folded sum/difference of antipodal x pairs: s[0..7] (16 channels) ----
template<bool SUB>
__device__ __forceinline__ void mkps(const __half* __restrict__ ldsh, int baseb,
                                     int dp, int dm, h2 (&s)[8])
{
    const int4* pp = (const int4*)((const char*)ldsh + baseb + dp);
    const int4* pm = (const int4*)((const char*)ldsh + baseb + dm);
    I4H xp0, xp1, xm0, xm1;
    xp0.v = pp[0]; xp1.v = pp[1]; xm0.v = pm[0]; xm1.v = pm[1];
#pragma unroll
    for (int q = 0; q < 4; ++q) {
        s[q]   = SUB ? __hsub2(xp0.h[q], xm0.h[q]) : __hadd2(xp0.h[q], xm0.h[q]);
        s[q+4] = SUB ? __hsub2(xp1.h[q], xm1.h[q]) : __hadd2(xp1.h[q], xm1.h[q]);
    }
}

// ---------------- conv passes (pair-folded) -------------------------------
// complex z rows: [0]=r_j0, [1]=i_j0, [2]=r_j1, [3]=i_j1

template<bool SUB>
__device__ __forceinline__ void conv2c_p(const __half* __restrict__ ldsh, int baseb,
    const int4* __restrict__ aA, const int4* __restrict__ aB,
    const int* __restrict__ edp, const int* __restrict__ edm,
    h2 (&zA)[4][8], h2 (&zB)[4][8])
{
#pragma unroll
    for (int r = 0; r < 4; ++r)
#pragma unroll
        for (int q = 0; q < 8; ++q) { zA[r][q] = __float2half2_rn(0.f); zB[r][q] = __float2half2_rn(0.f); }

#pragma unroll
    for (int k = 0; k < 3; ++k) {           // j0 only
        I4H ca, cb_; ca.v = aA[k]; cb_.v = aB[k];
        h2 s[8]; mkps<SUB>(ldsh, baseb, edp[k], edm[k], s);
#pragma unroll
        for (int q = 0; q < 4; ++q) {
            zA[0][q]   = __hfma2(ca.h[0],  s[q],   zA[0][q]);
            zA[1][q]   = __hfma2(ca.h[1],  s[q],   zA[1][q]);
            zB[0][q]   = __hfma2(cb_.h[0], s[q],   zB[0][q]);
            zB[1][q]   = __hfma2(cb_.h[1], s[q],   zB[1][q]);
            zA[0][q+4] = __hfma2(ca.h[0],  s[q+4], zA[0][q+4]);
            zA[1][q+4] = __hfma2(ca.h[1],  s[q+4], zA[1][q+4]);
            zB[0][q+4] = __hfma2(cb_.h[0], s[q+4], zB[0][q+4]);
            zB[1][q+4] = __hfma2(cb_.h[1], s[q+4], zB[1][q+4]);
        }
    }
#pragma unroll 2
    for (int k = 3; k < 13; ++k) {          // both j
        I4H ca, cb_; ca.v = aA[k]; cb_.v = aB[k];
        h2 s[8]; mkps<SUB>(ldsh, baseb, edp[k], edm[k], s);
#pragma unroll
        for (int q = 0; q < 4; ++q) {
            zA[0][q]   = __hfma2(ca.h[0],  s[q],   zA[0][q]);
            zA[1][q]   = __hfma2(ca.h[1],  s[q],   zA[1][q]);
            zA[2][q]   = __hfma2(ca.h[2],  s[q],   zA[2][q]);
            zA[3][q]   = __hfma2(ca.h[3],  s[q],   zA[3][q]);
            zB[0][q]   = __hfma2(cb_.h[0], s[q],   zB[0][q]);
            zB[1][q]   = __hfma2(cb_.h[1], s[q],   zB[1][q]);
            zB[2][q]   = __hfma2(cb_.h[2], s[q],   zB[2][q]);
            zB[3][q]   = __hfma2(cb_.h[3], s[q],   zB[3][q]);
            zA[0][q+4] = __hfma2(ca.h[0],  s[q+4], zA[0][q+4]);
            zA[1][q+4] = __hfma2(ca.h[1],  s[q+4], zA[1][q+4]);
            zA[2][q+4] = __hfma2(ca.h[2],  s[q+4], zA[2][q+4]);
            zA[3][q+4] = __hfma2(ca.h[3],  s[q+4], zA[3][q+4]);
            zB[0][q+4] = __hfma2(cb_.h[0], s[q+4], zB[0][q+4]);
            zB[1][q+4] = __hfma2(cb_.h[1], s[q+4], zB[1][q+4]);
            zB[2][q+4] = __hfma2(cb_.h[2], s[q+4], zB[2][q+4]);
            zB[3][q+4] = __hfma2(cb_.h[3], s[q+4], zB[3][q+4]);
        }
    }
#pragma unroll 2
    for (int k = 13; k < 46; ++k) {         // j1 only
        I4H ca, cb_; ca.v = aA[k]; cb_.v = aB[k];
        h2 s[8]; mkps<SUB>(ldsh, baseb, edp[k], edm[k], s);
#pragma unroll
        for (int q = 0; q < 4; ++q) {
            zA[2][q]   = __hfma2(ca.h[2],  s[q],   zA[2][q]);
            zA[3][q]   = __hfma2(ca.h[3],  s[q],   zA[3][q]);
            zB[2][q]   = __hfma2(cb_.h[2], s[q],   zB[2][q]);
            zB[3][q]   = __hfma2(cb_.h[3], s[q],   zB[3][q]);
            zA[2][q+4] = __hfma2(ca.h[2],  s[q+4], zA[2][q+4]);
            zA[3][q+4] = __hfma2(ca.h[3],  s[q+4], zA[3][q+4]);
            zB[2][q+4] = __hfma2(cb_.h[2], s[q+4], zB[2][q+4]);
            zB[3][q+4] = __hfma2(cb_.h[3], s[q+4], zB[3][q+4]);
        }
    }
}

// one complex (zC rows 0-3) + one real (zR rows 0,1) harmonic, SAME parity
template<bool SUB>
__device__ __forceinline__ void conv_cr_p(const __half* __restrict__ ldsh, int baseb,
    const int4* __restrict__ aC, const int4* __restrict__ aR,
    const int* __restrict__ edp, const int* __restrict__ edm,
    h2 (&zC)[4][8], h2 (&zR)[2][8])
{
#pragma unroll
    for (int q = 0; q < 8; ++q) {
        zC[0][q] = __float2half2_rn(0.f); zC[1][q] = __float2half2_rn(0.f);
        zC[2][q] = __float2half2_rn(0.f); zC[3][q] = __float2half2_rn(0.f);
        zR[0][q] = __float2half2_rn(0.f); zR[1][q] = __float2half2_rn(0.f);
    }
#pragma unroll
    for (int k = 0; k < 3; ++k) {           // j0 only
        I4H cc, cr; cc.v = aC[k]; cr.v = aR[k];
        h2 s[8]; mkps<SUB>(ldsh, baseb, edp[k], edm[k], s);
#pragma unroll
        for (int q = 0; q < 4; ++q) {
            zC[0][q]   = __hfma2(cc.h[0], s[q],   zC[0][q]);
            zC[1][q]   = __hfma2(cc.h[1], s[q],   zC[1][q]);
            zR[0][q]   = __hfma2(cr.h[0], s[q],   zR[0][q]);
            zC[0][q+4] = __hfma2(cc.h[0], s[q+4], zC[0][q+4]);
            zC[1][q+4] = __hfma2(cc.h[1], s[q+4], zC[1][q+4]);
            zR[0][q+4] = __hfma2(cr.h[0], s[q+4], zR[0][q+4]);
        }
    }
#pragma unroll 2
    for (int k = 3; k < 13; ++k) {          // both j
        I4H cc, cr; cc.v = aC[k]; cr.v = aR[k];
        h2 s[8]; mkps<SUB>(ldsh, baseb, edp[k], edm[k], s);
#pragma unroll
        for (int q = 0; q < 4; ++q) {
            zC[0][q]   = __hfma2(cc.h[0], s[q],   zC[0][q]);
            zC[1][q]   = __hfma2(cc.h[1], s[q],   zC[1][q]);
            zC[2][q]   = __hfma2(cc.h[2], s[q],   zC[2][q]);
            zC[3][q]   = __hfma2(cc.h[3], s[q],   zC[3][q]);
            zR[0][q]   = __hfma2(cr.h[0], s[q],   zR[0][q]);
            zR[1][q]   = __hfma2(cr.h[2], s[q],   zR[1][q]);
            zC[0][q+4] = __hfma2(cc.h[0], s[q+4], zC[0][q+4]);
            zC[1][q+4] = __hfma2(cc.h[1], s[q+4], zC[1][q+4]);
            zC[2][q+4] = __hfma2(cc.h[2], s[q+4], zC[2][q+4]);
            zC[3][q+4] = __hfma2(cc.h[3], s[q+4], zC[3][q+4]);
            zR[0][q+4] = __hfma2(cr.h[0], s[q+4], zR[0][q+4]);
            zR[1][q+4] = __hfma2(cr.h[2], s[q+4], zR[1][q+4]);
        }
    }
#pragma unroll 2
    for (int k = 13; k < 46; ++k) {         // j1 only
        I4H cc, cr; cc.v = aC[k]; cr.v = aR[k];
        h2 s[8]; mkps<SUB>(ldsh, baseb, edp[k], edm[k], s);
#pragma unroll
        for (int q = 0; q < 4; ++q) {
            zC[2][q]   = __hfma2(cc.h[2], s[q],   zC[2][q]);
            zC[3][q]   = __hfma2(cc.h[3], s[q],   zC[3][q]);
            zR[1][q]   = __hfma2(cr.h[2], s[q],   zR[1][q]);
            zC[2][q+4] = __hfma2(cc.h[2], s[q+4], zC[2][q+4]);
            zC[3][q+4] = __hfma2(cc.h[3], s[q+4], zC[3][q+4]);
            zR[1][q+4] = __hfma2(cr.h[2], s[q+4], zR[1][q+4]);
        }
    }
}

// single real harmonic (rows j0,j1)
template<bool SUB>
__device__ __forceinline__ void conv1r_p(const __half* __restrict__ ldsh, int baseb,
    const int4* __restrict__ aR,
    const int* __restrict__ edp, const int* __restrict__ edm, h2 (&zR)[2][8])
{
#pragma unroll
    for (int q = 0; q < 8; ++q) { zR[0][q] = __float2half2_rn(0.f); zR[1][q] = __float2half2_rn(0.f); }
#pragma unroll
    for (int k = 0; k < 3; ++k) {
        I4H cr; cr.v = aR[k];
        h2 s[8]; mkps<SUB>(ldsh, baseb, edp[k], edm[k], s);
#pragma unroll
        for (int q = 0; q < 4; ++q) {
            zR[0][q]   = __hfma2(cr.h[0], s[q],   zR[0][q]);
            zR[0][q+4] = __hfma2(cr.h[0], s[q+4], zR[0][q+4]);
        }
    }
#pragma unroll 2
    for (int k = 3; k < 13; ++k) {
        I4H cr; cr.v = aR[k];
        h2 s[8]; mkps<SUB>(ldsh, baseb, edp[k], edm[k], s);
#pragma unroll
        for (int q = 0; q < 4; ++q) {
            zR[0][q]   = __hfma2(cr.h[0], s[q],   zR[0][q]);
            zR[1][q]   = __hfma2(cr.h[2], s[q],   zR[1][q]);
            zR[0][q+4] = __hfma2(cr.h[0], s[q+4], zR[0][q+4]);
            zR[1][q+4] = __hfma2(cr.h[2], s[q+4], zR[1][q+4]);
        }
    }
#pragma unroll 2
    for (int k = 13; k < 46; ++k) {
        I4H cr; cr.v = aR[k];
        h2 s[8]; mkps<SUB>(ldsh, baseb, edp[k], edm[k], s);
#pragma unroll
        for (int q = 0; q < 4; ++q) {
            zR[1][q]   = __hfma2(cr.h[2], s[q],   zR[1][q]);
            zR[1][q+4] = __hfma2(cr.h[2], s[q+4], zR[1][q+4]);
        }
    }
}

// ---------------- mixing + spectrum + fused projection --------------------

#define CDEL (2*(LYY*LXX) + 2*LXX + 2)

// two complex harmonics of the SAME degree N: one projection pass
template<int N>
__device__ __forceinline__ void mixc2(const h2 (&zA)[4][8], const h2 (&zB)[4][8],
    const int4* __restrict__ wt2n, const float* __restrict__ pwT, float2 (&outa)[16])
{
    const float W = 2.f / (float)(2*N + 1);
#pragma unroll 2
    for (int f = 0; f < 32; ++f) {
        I4H w00, w01, w10, w11;
        w00.v = wt2n[f*4+0]; w01.v = wt2n[f*4+1];
        w10.v = wt2n[f*4+2]; w11.v = wt2n[f*4+3];
        h2 yrA = __float2half2_rn(0.f), yiA = __float2half2_rn(0.f);
        h2 yrB = __float2half2_rn(0.f), yiB = __float2half2_rn(0.f);
#pragma unroll
        for (int q = 0; q < 4; ++q) {
            yrA = __hfma2(w00.h[q], zA[0][q],   yrA);
            yrA = __hfma2(w01.h[q], zA[0][q+4], yrA);
            yrA = __hfma2(w10.h[q], zA[2][q],   yrA);
            yrA = __hfma2(w11.h[q], zA[2][q+4], yrA);
            yiA = __hfma2(w00.h[q], zA[1][q],   yiA);
            yiA = __hfma2(w01.h[q], zA[1][q+4], yiA);
            yiA = __hfma2(w10.h[q], zA[3][q],   yiA);
            yiA = __hfma2(w11.h[q], zA[3][q+4], yiA);
            yrB = __hfma2(w00.h[q], zB[0][q],   yrB);
            yrB = __hfma2(w01.h[q], zB[0][q+4], yrB);
            yrB = __hfma2(w10.h[q], zB[2][q],   yrB);
            yrB = __hfma2(w11.h[q], zB[2][q+4], yrB);
            yiB = __hfma2(w00.h[q], zB[1][q],   yiB);
            yiB = __hfma2(w01.h[q], zB[1][q+4], yiB);
            yiB = __hfma2(w10.h[q], zB[3][q],   yiB);
            yiB = __hfma2(w11.h[q], zB[3][q+4], yiB);
        }
        float ra = __low2float(yrA) + __high2float(yrA);
        float ia = __low2float(yiA) + __high2float(yiA);
        float rb = __low2float(yrB) + __high2float(yrB);
        float ib = __low2float(yiB) + __high2float(yiB);
        float s = (ra*ra + ia*ia + rb*rb + ib*ib) * W;
        const float2* pw2 = (const float2*)(pwT + (f*4 + N)*32);
#pragma unroll
        for (int k = 0; k < 16; ++k) {
            float2 t = pw2[k];
            outa[k].x = fmaf(t.x, s, outa[k].x);
            outa[k].y = fmaf(t.y, s, outa[k].y);
        }
    }
}

// one complex harmonic (zC) + one real harmonic (zR), same degree N
template<int N>
__device__ __forceinline__ void mix_cr(const h2 (&zC)[4][8], const h2 (&zR)[2][8],
    const int4* __restrict__ wt2n, const float* __restrict__ pwT, float2 (&outa)[16])
{
    const float Wc = 2.f / (float)(2*N + 1);
    const float Wr = 1.f / (float)(2*N + 1);
#pragma unroll 2
    for (int f = 0; f < 32; ++f) {
        I4H w00, w01, w10, w11;
        w00.v = wt2n[f*4+0]; w01.v = wt2n[f*4+1];
        w10.v = wt2n[f*4+2]; w11.v = wt2n[f*4+3];
        h2 yr = __float2half2_rn(0.f), yi = __float2half2_rn(0.f);
        h2 yR = __float2half2_rn(0.f);
#pragma unroll
        for (int q = 0; q < 4; ++q) {
            yr = __hfma2(w00.h[q], zC[0][q],   yr);
            yr = __hfma2(w01.h[q], zC[0][q+4], yr);
            yr = __hfma2(w10.h[q], zC[2][q],   yr);
            yr = __hfma2(w11.h[q], zC[2][q+4], yr);
            yi = __hfma2(w00.h[q], zC[1][q],   yi);
            yi = __hfma2(w01.h[q], zC[1][q+4], yi);
            yi = __hfma2(w10.h[q], zC[3][q],   yi);
            yi = __hfma2(w11.h[q], zC[3][q+4], yi);
            yR = __hfma2(w00.h[q], zR[0][q],   yR);
            yR = __hfma2(w01.h[q], zR[0][q+4], yR);
            yR = __hfma2(w10.h[q], zR[1][q],   yR);
            yR = __hfma2(w11.h[q], zR[1][q+4], yR);
        }
        float rc = __low2float(yr) + __high2float(yr);
        float ic = __low2float(yi) + __high2float(yi);
        float rr = __low2float(yR) + __high2float(yR);
        float s = (rc*rc + ic*ic) * Wc + rr*rr * Wr;
        const float2* pw2 = (const float2*)(pwT + (f*4 + N)*32);
#pragma unroll
        for (int k = 0; k < 16; ++k) {
            float2 t = pw2[k];
            outa[k].x = fmaf(t.x, s, outa[k].x);
            outa[k].y = fmaf(t.y, s, outa[k].y);
        }
    }
}

// single real harmonic; optional central conv fold (h0)
template<int N, bool CENTRAL>
__device__ __forceinline__ void mixr(const h2 (&z)[2][8],
    const int4* __restrict__ wt2n, const int4* __restrict__ cw2,
    const float* __restrict__ cbp, const __half* __restrict__ ldsh, int baseb,
    const float* __restrict__ pwT, float2 (&outa)[16])
{
    const float W = 1.f / (float)(2*N + 1);
    h2 xc[8];
    if (CENTRAL) {
        const int4* pc = (const int4*)((const char*)ldsh + baseb + CDEL*POSB);
        I4H xc0, xc1; xc0.v = pc[0]; xc1.v = pc[1];
#pragma unroll
        for (int q = 0; q < 4; ++q) { xc[q] = xc0.h[q]; xc[q+4] = xc1.h[q]; }
    }
#pragma unroll 2
    for (int f = 0; f < 32; ++f) {
        I4H w00, w01, w10, w11;
        w00.v = wt2n[f*4+0]; w01.v = wt2n[f*4+1];
        w10.v = wt2n[f*4+2]; w11.v = wt2n[f*4+3];
        h2 yr = __float2half2_rn(0.f);
#pragma unroll
        for (int q = 0; q < 4; ++q) {
            yr = __hfma2(w00.h[q], z[0][q],   yr);
            yr = __hfma2(w01.h[q], z[0][q+4], yr);
            yr = __hfma2(w10.h[q], z[1][q],   yr);
            yr = __hfma2(w11.h[q], z[1][q+4], yr);
        }
        float yrf = __low2float(yr) + __high2float(yr);
        if (CENTRAL) {
            I4H c0, c1; c0.v = cw2[f*2]; c1.v = cw2[f*2+1];
            h2 acc = __float2half2_rn(0.f);
#pragma unroll
            for (int q = 0; q < 4; ++q) {
                acc = __hfma2(c0.h[q], xc[q],   acc);
                acc = __hfma2(c1.h[q], xc[q+4], acc);
            }
            yrf += cbp[f] + __low2float(acc) + __high2float(acc);
        }
        float s = yrf*yrf * W;
        const float2* pw2 = (const float2*)(pwT + (f*4 + N)*32);
#pragma unroll
        for (int k = 0; k < 16; ++k) {
            float2 t = pw2[k];
            outa[k].x = fmaf(t.x, s, outa[k].x);
            outa[k].y = fmaf(t.y, s, outa[k].y);
        }
    }
}

__global__ __launch_bounds__(512) void ssh_main(
    const float* __restrict__ x, const float* __restrict__ cb,
    const char* __restrict__ wsb, float* __restrict__ out)
{
    __shared__ __align__(16) __half ldsh[NPOS * CPAD];   // 36864 B
    const int tid = threadIdx.x;
    const int x0 = blockIdx.x * TX, y0 = blockIdx.y * TY, z0 = blockIdx.z * TZ;

    // stage x -> f16 LDS, channel-fastest, 2 channels per write (b32)
    for (int i = tid; i < NPOS * 8; i += 512) {
        int cp = i / NPOS;
        int pos = i - cp * NPOS;
        int lx = pos % LXX; int t1 = pos / LXX;
        int ly = t1 % LYY;  int lz = t1 / LYY;
        int gx = x0 + lx - 2, gy = y0 + ly - 2, gz = z0 + lz - 2;
        h2 hv = __float2half2_rn(0.f);
        if ((unsigned)gx < 48u && (unsigned)gy < 48u && (unsigned)gz < 48u) {
            int gi = ((2*cp*48 + gz)*48 + gy)*48 + gx;
            hv = __floats2half2_rn(x[gi], x[gi + 48*48*48]);
        }
        *(h2*)(ldsh + pos*CPAD + 2*cp) = hv;
    }
    __syncthreads();

    const int hg  = __builtin_amdgcn_readfirstlane(tid >> 7);   // 0..3, wave-uniform
    const int vid = tid & 127;
    const int tx = vid & 7, ty = (vid >> 3) & 3, tz = vid >> 5;
    const int baseb = (tz*(LYY*LXX) + ty*LXX + tx) * POSB;

    const int4* __restrict__ pat  = (const int4*)(wsb + PAT_B);
    const int*  __restrict__ edp  = (const int*)(wsb + ED_B);
    const int*  __restrict__ edm  = edp + 46;
    const int4* __restrict__ wt2  = (const int4*)(wsb + WT2_B);
    const int4* __restrict__ cw2  = (const int4*)(wsb + CW2_B);
    const float* __restrict__ pwT = (const float*)(wsb + PWT_B);
    const float* __restrict__ obase = (const float*)(wsb + OB_B);

    float2 outa[16];
#pragma unroll
    for (int k = 0; k < 16; ++k) outa[k] = make_float2(0.f, 0.f);

    if (hg == 0) {
        // n=3 odd (SUB): h13,h14 complex pair
        h2 zA[4][8], zB[4][8];
        conv2c_p<true>(ldsh, baseb, pat + 13*46, pat + 14*46, edp, edm, zA, zB);
        mixc2<3>(zA, zB, wt2 + 3*128, pwT, outa);
    } else if (hg == 1) {
        // n=3 odd: h15 (complex) + h12 (real); n=0 even: h0 + central
        h2 zC[4][8], zR[2][8];
        conv_cr_p<true>(ldsh, baseb, pat + 15*46, pat + 12*46, edp, edm, zC, zR);
        mix_cr<3>(zC, zR, wt2 + 3*128, pwT, outa);
        h2 zR0[2][8];
        conv1r_p<false>(ldsh, baseb, pat + 0*46, edp, edm, zR0);
        mixr<0,true>(zR0, wt2 + 0*128, cw2, cb, ldsh, baseb, pwT, outa);
    } else if (hg == 2) {
        // n=2 even (ADD): h7,h8 complex pair
        h2 zA[4][8], zB[4][8];
        conv2c_p<false>(ldsh, baseb, pat + 7*46, pat + 8*46, edp, edm, zA, zB);
        mixc2<2>(zA, zB, wt2 + 2*128, pwT, outa);
    } else {
        // n=1 odd: h3 (complex) + h2 (real); n=2 even: h6
        h2 zC[4][8], zR[2][8];
        conv_cr_p<true>(ldsh, baseb, pat + 3*46, pat + 2*46, edp, edm, zC, zR);
        mix_cr<1>(zC, zR, wt2 + 1*128, pwT, outa);
        h2 zR0[2][8];
        conv1r_p<false>(ldsh, baseb, pat + 6*46, edp, edm, zR0);
        mixr<2,false>(zR0, wt2 + 2*128, cw2, cb, ldsh, baseb, pwT, outa);
    }

    // ---- 2-stage merge through dead x-tile LDS (f32, stride 33) ----
    __syncthreads();
    float* lmerge = (float*)ldsh;
    if (hg == 1) {
#pragma unroll
        for (int k = 0; k < 16; ++k) {
            lmerge[vid*33 + 2*k]     = outa[k].x;
            lmerge[vid*33 + 2*k + 1] = outa[k].y;
        }
    } else if (hg == 3) {
#pragma unroll
        for (int k = 0; k < 16; ++k) {
            lmerge[4224 + vid*33 + 2*k]     = outa[k].x;
            lmerge[4224 + vid*33 + 2*k + 1] = outa[k].y;
        }
    }
    __syncthreads();
    if (hg == 0) {
#pragma unroll
        for (int k = 0; k < 16; ++k) {
            outa[k].x += lmerge[vid*33 + 2*k];
            outa[k].y += lmerge[vid*33 + 2*k + 1];
        }
    } else if (hg == 2) {
#pragma unroll
        for (int k = 0; k < 16; ++k) {
            outa[k].x += lmerge[4224 + vid*33 + 2*k];
            outa[k].y += lmerge[4224 + vid*33 + 2*k + 1];
        }
#pragma unroll
        for (int k = 0; k < 16; ++k) {
            lmerge[4224 + vid*33 + 2*k]     = outa[k].x;
            lmerge[4224 + vid*33 + 2*k + 1] = outa[k].y;
        }
    }
    __syncthreads();
    if (hg == 0) {
        const int gz = z0 + tz, gy = y0 + ty, gx = x0 + tx;
#pragma unroll
        for (int k = 0; k < 16; ++k) {
            float v0 = obase[2*k]   + outa[k].x + lmerge[4224 + vid*33 + 2*k];
            float v1 = obase[2*k+1] + outa[k].y + lmerge[4224 + vid*33 + 2*k + 1];
            out[(((2*k)*48   + gz)*48 + gy)*48 + gx] = fmaxf(v0, 0.f);
            out[(((2*k+1)*48 + gz)*48 + gy)*48 + gx] = fmaxf(v1, 0.f);
        }
    }
}

extern "C" void kernel_launch(void* const* d_in, const int* in_sizes, int n_in,
                              void* d_out, int out_size, void* d_ws, size_t ws_size,
                              hipStream_t stream) {
    const float* x  = (const float*)d_in[0];
    const float* w  = (const float*)d_in[1];
    const float* cw = (const float*)d_in[2];
    const float* cb = (const float*)d_in[3];
    const float* sb = (const float*)d_in[4];
    const float* pw = (const float*)d_in[5];
    const float* pb = (const float*)d_in[6];
    float* out = (float*)d_out;
    char* wsb = (char*)d_ws;

    ssh_init<<<dim3(1), dim3(256), 0, stream>>>(w, cw, pw, sb, pb, wsb);
    ssh_main<<<dim3(48/TX, 48/TY, 48/TZ), dim3(512), 0, stream>>>(x, cb, wsb, out);
}

// Round 14
// 158.084 us; speedup vs baseline: 1.2619x; 1.2619x over previous
//
#include <hip/hip_runtime.h>
#include <hip/hip_fp16.h>
#include <math.h>

// ---------------------------------------------------------------------------
// SSHConv3D fused, round 14: REVERT to round-11 (best measured: 158.1 us,
// absmax 0.0625). r13's parity folding regressed (halved fma density exposed
// LDS latency: VALUBusy 60->37). r11 = 8x4x4 tile, 4-way harmonic split,
// 512-thread blocks, m>=0 conjugate symmetry, packed-f16 datapath, paired
// same-degree projection, 2-stage f32 merge via dead x-tile LDS.
//
// ws layout (bytes):
//   [0,     23552) atab2 : h2[16 h][92 e][4] = {(ar0),(ai0),(ar1),(ai1)} repl. pairs
//   [23552, 31744) wT2   : h2[n][f][j][8 cp]
//   [31744, 32768) cw2   : h2[f][8 cp]
//   [32768, 49152) pwT   : f32[(f*4+n)][fo]
//   [49152, 49280) obase : f32[32]
//   [49280, 49648) edelta: int[92] byte offsets (pre-scaled by 48)
// Entry segments: [0,6)=j0-only, [6,26)=both j, [26,92)=j1-only.
// Work split: g0={h13,h14}, g1={h15,h12,h0+central}, g2={h7,h8}, g3={h6,h2,h3}.
// ---------------------------------------------------------------------------

#define TX 8
#define TY 4
#define TZ 4
#define LXX 12
#define LYY 8
#define LZZ 8
#define NPOS 768
#define CPAD 24
#define POSB 48

#define ATAB2_B 0
#define WT2_B   23552
#define CW2_B   31744
#define PWT_B   32768
#define OB_B    49152
#define ED_B    49280

typedef __half2 h2;
union I4H { int4 v; h2 h[4]; };

__global__ __launch_bounds__(256) void ssh_init(
    const float* __restrict__ w, const float* __restrict__ cw,
    const float* __restrict__ proj_w, const float* __restrict__ spec_bias,
    const float* __restrict__ proj_b, char* __restrict__ wsb)
{
    __shared__ float shr[125][16];
    __shared__ float shi[125][16];
    __shared__ float prof[125][2];
    __shared__ float norms[2][16];
    __shared__ int epos[92];
    const int tid = threadIdx.x;
    const float fourpi = 4.0f * 3.14159265358979323846f;

    for (int p = tid; p < 125; p += 256) {
        int d2 = p % 5, d1 = (p / 5) % 5, d0 = p / 25;
        float xc = (float)(d1 - 2), yc = (float)(d0 - 2), zc = (float)(d2 - 2);
        float r2 = xc*xc + yc*yc + zc*zc;
        float r  = sqrtf(r2);
        float phi = atan2f(yc, xc);
        float ct = (r > 0.f) ? (zc / r) : 0.f;
        float st = sqrtf(fmaxf(0.f, 1.f - ct*ct));
        float c1 = cosf(phi), s1 = sinf(phi);
        float c2 = c1*c1 - s1*s1, s2 = 2.f*s1*c1;
        float c3 = c2*c1 - s2*s1, s3 = s2*c1 + c2*s1;
        float P10 = ct,              P11 = -st;
        float P20 = 0.5f*(3.f*ct*ct - 1.f), P21 = -3.f*ct*st, P22 = 3.f*st*st;
        float P30 = 0.5f*(5.f*ct*ct*ct - 3.f*ct);
        float P31 = -1.5f*(5.f*ct*ct - 1.f)*st;
        float P32 = 15.f*ct*st*st;
        float P33 = -15.f*st*st*st;
        float N00 = sqrtf(1.f/fourpi);
        float N10 = sqrtf(3.f/fourpi);
        float N11 = sqrtf(3.f/fourpi * 0.5f);
        float N20 = sqrtf(5.f/fourpi);
        float N21 = sqrtf(5.f/fourpi / 6.f);
        float N22 = sqrtf(5.f/fourpi / 24.f);
        float N30 = sqrtf(7.f/fourpi);
        float N31 = sqrtf(7.f/fourpi / 12.f);
        float N32 = sqrtf(7.f/fourpi / 120.f);
        float N33 = sqrtf(7.f/fourpi / 720.f);
        float b;
        shr[p][0] = N00;               shi[p][0] = 0.f;
        shr[p][2] = N10*P10;           shi[p][2] = 0.f;
        b = N11*P11;
        shr[p][3] =  b*c1;             shi[p][3] =  b*s1;
        shr[p][1] = -b*c1;             shi[p][1] =  b*s1;
        shr[p][6] = N20*P20;           shi[p][6] = 0.f;
        b = N21*P21;
        shr[p][7] =  b*c1;             shi[p][7] =  b*s1;
        shr[p][5] = -b*c1;             shi[p][5] =  b*s1;
        b = N22*P22;
        shr[p][8] =  b*c2;             shi[p][8] =  b*s2;
        shr[p][4] =  b*c2;             shi[p][4] = -b*s2;
        shr[p][12] = N30*P30;          shi[p][12] = 0.f;
        b = N31*P31;
        shr[p][13] =  b*c1;            shi[p][13] =  b*s1;
        shr[p][11] = -b*c1;            shi[p][11] =  b*s1;
        b = N32*P32;
        shr[p][14] =  b*c2;            shi[p][14] =  b*s2;
        shr[p][10] =  b*c2;            shi[p][10] = -b*s2;
        b = N33*P33;
        shr[p][15] =  b*c3;            shi[p][15] =  b*s3;
        shr[p][9]  = -b*c3;            shi[p][9]  =  b*s3;
        prof[p][0] = fmaxf(0.f, 1.f - fabsf(r - 1.f));
        prof[p][1] = fmaxf(0.f, 1.f - fabsf(r - 2.f));
    }
    __syncthreads();

    if (tid < 32) {
        int j = tid >> 4, h = tid & 15;
        float acc = 0.f;
        for (int p = 0; p < 125; ++p) {
            float pr = prof[p][j];
            acc += pr*pr*(shr[p][h]*shr[p][h] + shi[p][h]*shi[p][h]);
        }
        float nn = sqrtf(acc);
        norms[j][h] = (nn > 0.f) ? nn : 1.f;
    }
    // entry ordering via rank (cls0 base 0, cls1 base 6, cls2 base 26)
    if (tid < 125) {
        int p = tid;
        int d2 = p % 5, d1 = (p / 5) % 5, d0 = p / 25;
        int ix = d1 - 2, iy = d0 - 2, iz = d2 - 2;
        int r2i = ix*ix + iy*iy + iz*iz;
        int cls = (r2i == 1) ? 0 : (r2i == 2 || r2i == 3) ? 1
                : (r2i == 4 || r2i == 5 || r2i == 6 || r2i == 8) ? 2 : -1;
        if (cls >= 0) {
            int rank = (cls == 0) ? 0 : (cls == 1) ? 6 : 26;
            for (int q = 0; q < p; ++q) {
                int e2 = q % 5, e1 = (q / 5) % 5, e0 = q / 25;
                int jx = e1 - 2, jy = e0 - 2, jz = e2 - 2;
                int s2i = jx*jx + jy*jy + jz*jz;
                int c2i = (s2i == 1) ? 0 : (s2i == 2 || s2i == 3) ? 1
                       : (s2i == 4 || s2i == 5 || s2i == 6 || s2i == 8) ? 2 : -1;
                rank += (c2i == cls) ? 1 : 0;
            }
            epos[rank] = p;
            ((int*)(wsb + ED_B))[rank] = (d0*(LYY*LXX) + d1*LXX + d2) * POSB;
        }
    }
    __syncthreads();

    h2* at2 = (h2*)(wsb + ATAB2_B);
    for (int t = tid; t < 92*16; t += 256) {
        int e = t >> 4, h = t & 15;
        int p = epos[e];
        float c0 = prof[p][0] / norms[0][h];
        float c1v = prof[p][1] / norms[1][h];
        at2[(h*92+e)*4 + 0] = __float2half2_rn(c0*shr[p][h]);
        at2[(h*92+e)*4 + 1] = __float2half2_rn(c0*shi[p][h]);
        at2[(h*92+e)*4 + 2] = __float2half2_rn(c1v*shr[p][h]);
        at2[(h*92+e)*4 + 3] = __float2half2_rn(c1v*shi[p][h]);
    }
    // wT2: h2 index = n*512 + f*16 + j*8 + cp
    h2* wt2h = (h2*)(wsb + WT2_B);
    for (int t = tid; t < 2048; t += 256) {
        int n = t >> 9, f = (t >> 4) & 31, j = (t >> 3) & 1, cp = t & 7;
        float a = w[((2*cp*32 + f)*2 + j)*4 + n];
        float b = w[(((2*cp+1)*32 + f)*2 + j)*4 + n];
        wt2h[t] = __halves2half2(__float2half(a), __float2half(b));
    }
    // cw2: h2 index = f*8 + cp
    h2* cw2h = (h2*)(wsb + CW2_B);
    for (int t = tid; t < 256; t += 256) {
        int f = t >> 3, cp = t & 7;
        cw2h[t] = __halves2half2(__float2half(cw[f*16 + 2*cp]),
                                 __float2half(cw[f*16 + 2*cp + 1]));
    }
    // pwT f32 [(f*4+n)][fo]
    float* pwT = (float*)(wsb + PWT_B);
    for (int t = tid; t < 4096; t += 256) {
        int i = t >> 5, fo = t & 31;
        pwT[t] = proj_w[fo*128 + i];
    }
    if (tid < 32) {
        float acc = proj_b[tid];
        for (int i = 0; i < 128; ++i) acc += proj_w[tid*128 + i] * spec_bias[i];
        ((float*)(wsb + OB_B))[tid] = acc;
    }
}

// ---------------- conv passes --------------------------------------------
// complex z rows: [0]=r_j0, [1]=i_j0, [2]=r_j1, [3]=i_j1

__device__ __forceinline__ void conv2c(const __half* __restrict__ ldsh, int baseb,
    const int4* __restrict__ aA, const int4* __restrict__ aB,
    const int* __restrict__ ed, h2 (&zA)[4][8], h2 (&zB)[4][8])
{
#pragma unroll
    for (int r = 0; r < 4; ++r)
#pragma unroll
        for (int q = 0; q < 8; ++q) { zA[r][q] = __float2half2_rn(0.f); zB[r][q] = __float2half2_rn(0.f); }

#pragma unroll 3
    for (int e = 0; e < 6; ++e) {           // j0 only
        I4H ca, cb_, x0, x1;
        ca.v = aA[e]; cb_.v = aB[e];
        const int4* p = (const int4*)((const char*)ldsh + baseb + ed[e]);
        x0.v = p[0]; x1.v = p[1];
#pragma unroll
        for (int q = 0; q < 4; ++q) {
            zA[0][q]   = __hfma2(ca.h[0],  x0.h[q], zA[0][q]);
            zA[1][q]   = __hfma2(ca.h[1],  x0.h[q], zA[1][q]);
            zB[0][q]   = __hfma2(cb_.h[0], x0.h[q], zB[0][q]);
            zB[1][q]   = __hfma2(cb_.h[1], x0.h[q], zB[1][q]);
            zA[0][q+4] = __hfma2(ca.h[0],  x1.h[q], zA[0][q+4]);
            zA[1][q+4] = __hfma2(ca.h[1],  x1.h[q], zA[1][q+4]);
            zB[0][q+4] = __hfma2(cb_.h[0], x1.h[q], zB[0][q+4]);
            zB[1][q+4] = __hfma2(cb_.h[1], x1.h[q], zB[1][q+4]);
        }
    }
#pragma unroll 4
    for (int e = 6; e < 26; ++e) {          // both j
        I4H ca, cb_, x0, x1;
        ca.v = aA[e]; cb_.v = aB[e];
        const int4* p = (const int4*)((const char*)ldsh + baseb + ed[e]);
        x0.v = p[0]; x1.v = p[1];
#pragma unroll
        for (int q = 0; q < 4; ++q) {
            zA[0][q]   = __hfma2(ca.h[0],  x0.h[q], zA[0][q]);
            zA[1][q]   = __hfma2(ca.h[1],  x0.h[q], zA[1][q]);
            zA[2][q]   = __hfma2(ca.h[2],  x0.h[q], zA[2][q]);
            zA[3][q]   = __hfma2(ca.h[3],  x0.h[q], zA[3][q]);
            zB[0][q]   = __hfma2(cb_.h[0], x0.h[q], zB[0][q]);
            zB[1][q]   = __hfma2(cb_.h[1], x0.h[q], zB[1][q]);
            zB[2][q]   = __hfma2(cb_.h[2], x0.h[q], zB[2][q]);
            zB[3][q]   = __hfma2(cb_.h[3], x0.h[q], zB[3][q]);
            zA[0][q+4] = __hfma2(ca.h[0],  x1.h[q], zA[0][q+4]);
            zA[1][q+4] = __hfma2(ca.h[1],  x1.h[q], zA[1][q+4]);
            zA[2][q+4] = __hfma2(ca.h[2],  x1.h[q], zA[2][q+4]);
            zA[3][q+4] = __hfma2(ca.h[3],  x1.h[q], zA[3][q+4]);
            zB[0][q+4] = __hfma2(cb_.h[0], x1.h[q], zB[0][q+4]);
            zB[1][q+4] = __hfma2(cb_.h[1], x1.h[q], zB[1][q+4]);
            zB[2][q+4] = __hfma2(cb_.h[2], x1.h[q], zB[2][q+4]);
            zB[3][q+4] = __hfma2(cb_.h[3], x1.h[q], zB[3][q+4]);
        }
    }
#pragma unroll 3
    for (int e = 26; e < 92; ++e) {         // j1 only
        I4H ca, cb_, x0, x1;
        ca.v = aA[e]; cb_.v = aB[e];
        const int4* p = (const int4*)((const char*)ldsh + baseb + ed[e]);
        x0.v = p[0]; x1.v = p[1];
#pragma unroll
        for (int q = 0; q < 4; ++q) {
            zA[2][q]   = __hfma2(ca.h[2],  x0.h[q], zA[2][q]);
            zA[3][q]   = __hfma2(ca.h[3],  x0.h[q], zA[3][q]);
            zB[2][q]   = __hfma2(cb_.h[2], x0.h[q], zB[2][q]);
            zB[3][q]   = __hfma2(cb_.h[3], x0.h[q], zB[3][q]);
            zA[2][q+4] = __hfma2(ca.h[2],  x1.h[q], zA[2][q+4]);
            zA[3][q+4] = __hfma2(ca.h[3],  x1.h[q], zA[3][q+4]);
            zB[2][q+4] = __hfma2(cb_.h[2], x1.h[q], zB[2][q+4]);
            zB[3][q+4] = __hfma2(cb_.h[3], x1.h[q], zB[3][q+4]);
        }
    }
}

__device__ __forceinline__ void conv1c(const __half* __restrict__ ldsh, int baseb,
    const int4* __restrict__ aA, const int* __restrict__ ed, h2 (&zA)[4][8])
{
#pragma unroll
    for (int r = 0; r < 4; ++r)
#pragma unroll
        for (int q = 0; q < 8; ++q) zA[r][q] = __float2half2_rn(0.f);

#pragma unroll 3
    for (int e = 0; e < 6; ++e) {
        I4H ca, x0, x1;
        ca.v = aA[e];
        const int4* p = (const int4*)((const char*)ldsh + baseb + ed[e]);
        x0.v = p[0]; x1.v = p[1];
#pragma unroll
        for (int q = 0; q < 4; ++q) {
            zA[0][q]   = __hfma2(ca.h[0], x0.h[q], zA[0][q]);
            zA[1][q]   = __hfma2(ca.h[1], x0.h[q], zA[1][q]);
            zA[0][q+4] = __hfma2(ca.h[0], x1.h[q], zA[0][q+4]);
            zA[1][q+4] = __hfma2(ca.h[1], x1.h[q], zA[1][q+4]);
        }
    }
#pragma unroll 4
    for (int e = 6; e < 26; ++e) {
        I4H ca, x0, x1;
        ca.v = aA[e];
        const int4* p = (const int4*)((const char*)ldsh + baseb + ed[e]);
        x0.v = p[0]; x1.v = p[1];
#pragma unroll
        for (int q = 0; q < 4; ++q) {
            zA[0][q]   = __hfma2(ca.h[0], x0.h[q], zA[0][q]);
            zA[1][q]   = __hfma2(ca.h[1], x0.h[q], zA[1][q]);
            zA[2][q]   = __hfma2(ca.h[2], x0.h[q], zA[2][q]);
            zA[3][q]   = __hfma2(ca.h[3], x0.h[q], zA[3][q]);
            zA[0][q+4] = __hfma2(ca.h[0], x1.h[q], zA[0][q+4]);
            zA[1][q+4] = __hfma2(ca.h[1], x1.h[q], zA[1][q+4]);
            zA[2][q+4] = __hfma2(ca.h[2], x1.h[q], zA[2][q+4]);
            zA[3][q+4] = __hfma2(ca.h[3], x1.h[q], zA[3][q+4]);
        }
    }
#pragma unroll 3
    for (int e = 26; e < 92; ++e) {
        I4H ca, x0, x1;
        ca.v = aA[e];
        const int4* p = (const int4*)((const char*)ldsh + baseb + ed[e]);
        x0.v = p[0]; x1.v = p[1];
#pragma unroll
        for (int q = 0; q < 4; ++q) {
            zA[2][q]   = __hfma2(ca.h[2], x0.h[q], zA[2][q]);
            zA[3][q]   = __hfma2(ca.h[3], x0.h[q], zA[3][q]);
            zA[2][q+4] = __hfma2(ca.h[2], x1.h[q], zA[2][q+4]);
            zA[3][q+4] = __hfma2(ca.h[3], x1.h[q], zA[3][q+4]);
        }
    }
}

// two REAL harmonics A,B (m=0).  z rows: [0]=A_j0, [1]=A_j1, [2]=B_j0, [3]=B_j1
__device__ __forceinline__ void conv2r(const __half* __restrict__ ldsh, int baseb,
    const int4* __restrict__ aA, const int4* __restrict__ aB,
    const int* __restrict__ ed, h2 (&z)[4][8])
{
#pragma unroll
    for (int r = 0; r < 4; ++r)
#pragma unroll
        for (int q = 0; q < 8; ++q) z[r][q] = __float2half2_rn(0.f);

#pragma unroll 3
    for (int e = 0; e < 6; ++e) {           // j0 only
        I4H ca, cb_, x0, x1;
        ca.v = aA[e]; cb_.v = aB[e];
        const int4* p = (const int4*)((const char*)ldsh + baseb + ed[e]);
        x0.v = p[0]; x1.v = p[1];
#pragma unroll
        for (int q = 0; q < 4; ++q) {
            z[0][q]   = __hfma2(ca.h[0],  x0.h[q], z[0][q]);
            z[2][q]   = __hfma2(cb_.h[0], x0.h[q], z[2][q]);
            z[0][q+4] = __hfma2(ca.h[0],  x1.h[q], z[0][q+4]);
            z[2][q+4] = __hfma2(cb_.h[0], x1.h[q], z[2][q+4]);
        }
    }
#pragma unroll 4
    for (int e = 6; e < 26; ++e) {          // both j
        I4H ca, cb_, x0, x1;
        ca.v = aA[e]; cb_.v = aB[e];
        const int4* p = (const int4*)((const char*)ldsh + baseb + ed[e]);
        x0.v = p[0]; x1.v = p[1];
#pragma unroll
        for (int q = 0; q < 4; ++q) {
            z[0][q]   = __hfma2(ca.h[0],  x0.h[q], z[0][q]);
            z[1][q]   = __hfma2(ca.h[2],  x0.h[q], z[1][q]);
            z[2][q]   = __hfma2(cb_.h[0], x0.h[q], z[2][q]);
            z[3][q]   = __hfma2(cb_.h[2], x0.h[q], z[3][q]);
            z[0][q+4] = __hfma2(ca.h[0],  x1.h[q], z[0][q+4]);
            z[1][q+4] = __hfma2(ca.h[2],  x1.h[q], z[1][q+4]);
            z[2][q+4] = __hfma2(cb_.h[0], x1.h[q], z[2][q+4]);
            z[3][q+4] = __hfma2(cb_.h[2], x1.h[q], z[3][q+4]);
        }
    }
#pragma unroll 3
    for (int e = 26; e < 92; ++e) {         // j1 only
        I4H ca, cb_, x0, x1;
        ca.v = aA[e]; cb_.v = aB[e];
        const int4* p = (const int4*)((const char*)ldsh + baseb + ed[e]);
        x0.v = p[0]; x1.v = p[1];
#pragma unroll
        for (int q = 0; q < 4; ++q) {
            z[1][q]   = __hfma2(ca.h[2],  x0.h[q], z[1][q]);
            z[3][q]   = __hfma2(cb_.h[2], x0.h[q], z[3][q]);
            z[1][q+4] = __hfma2(ca.h[2],  x1.h[q], z[1][q+4]);
            z[3][q+4] = __hfma2(cb_.h[2], x1.h[q], z[3][q+4]);
        }
    }
}

// ---------------- mixing + spectrum + fused projection --------------------

#define CDEL (2*(LYY*LXX) + 2*LXX + 2)

// two complex harmonics of the SAME degree N: one projection pass
template<int N>
__device__ __forceinline__ void mixc2(const h2 (&zA)[4][8], const h2 (&zB)[4][8],
    const int4* __restrict__ wt2n, const float* __restrict__ pwT, float2 (&outa)[16])
{
    const float W = 2.f / (float)(2*N + 1);
#pragma unroll 2
    for (int f = 0; f < 32; ++f) {
        I4H w00, w01, w10, w11;
        w00.v = wt2n[f*4+0]; w01.v = wt2n[f*4+1];
        w10.v = wt2n[f*4+2]; w11.v = wt2n[f*4+3];
        h2 yrA = __float2half2_rn(0.f), yiA = __float2half2_rn(0.f);
        h2 yrB = __float2half2_rn(0.f), yiB = __float2half2_rn(0.f);
#pragma unroll
        for (int q = 0; q < 4; ++q) {
            yrA = __hfma2(w00.h[q], zA[0][q],   yrA);
            yrA = __hfma2(w01.h[q], zA[0][q+4], yrA);
            yrA = __hfma2(w10.h[q], zA[2][q],   yrA);
            yrA = __hfma2(w11.h[q], zA[2][q+4], yrA);
            yiA = __hfma2(w00.h[q], zA[1][q],   yiA);
            yiA = __hfma2(w01.h[q], zA[1][q+4], yiA);
            yiA = __hfma2(w10.h[q], zA[3][q],   yiA);
            yiA = __hfma2(w11.h[q], zA[3][q+4], yiA);
            yrB = __hfma2(w00.h[q], zB[0][q],   yrB);
            yrB = __hfma2(w01.h[q], zB[0][q+4], yrB);
            yrB = __hfma2(w10.h[q], zB[2][q],   yrB);
            yrB = __hfma2(w11.h[q], zB[2][q+4], yrB);
            yiB = __hfma2(w00.h[q], zB[1][q],   yiB);
            yiB = __hfma2(w01.h[q], zB[1][q+4], yiB);
            yiB = __hfma2(w10.h[q], zB[3][q],   yiB);
            yiB = __hfma2(w11.h[q], zB[3][q+4], yiB);
        }
        float ra = __low2float(yrA) + __high2float(yrA);
        float ia = __low2float(yiA) + __high2float(yiA);
        float rb = __low2float(yrB) + __high2float(yrB);
        float ib = __low2float(yiB) + __high2float(yiB);
        float s = (ra*ra + ia*ia + rb*rb + ib*ib) * W;
        const float2* pw2 = (const float2*)(pwT + (f*4 + N)*32);
#pragma unroll
        for (int k = 0; k < 16; ++k) {
            float2 t = pw2[k];
            outa[k].x = fmaf(t.x, s, outa[k].x);
            outa[k].y = fmaf(t.y, s, outa[k].y);
        }
    }
}

// one complex harmonic (zC) + one real harmonic (zR rows RR,RR+1), same degree N
template<int RR, int N>
__device__ __forceinline__ void mix_cr(const h2 (&zC)[4][8], const h2 (&zR)[4][8],
    const int4* __restrict__ wt2n, const float* __restrict__ pwT, float2 (&outa)[16])
{
    const float Wc = 2.f / (float)(2*N + 1);
    const float Wr = 1.f / (float)(2*N + 1);
#pragma unroll 2
    for (int f = 0; f < 32; ++f) {
        I4H w00, w01, w10, w11;
        w00.v = wt2n[f*4+0]; w01.v = wt2n[f*4+1];
        w10.v = wt2n[f*4+2]; w11.v = wt2n[f*4+3];
        h2 yr = __float2half2_rn(0.f), yi = __float2half2_rn(0.f);
        h2 yR = __float2half2_rn(0.f);
#pragma unroll
        for (int q = 0; q < 4; ++q) {
            yr = __hfma2(w00.h[q], zC[0][q],   yr);
            yr = __hfma2(w01.h[q], zC[0][q+4], yr);
            yr = __hfma2(w10.h[q], zC[2][q],   yr);
            yr = __hfma2(w11.h[q], zC[2][q+4], yr);
            yi = __hfma2(w00.h[q], zC[1][q],   yi);
            yi = __hfma2(w01.h[q], zC[1][q+4], yi);
            yi = __hfma2(w10.h[q], zC[3][q],   yi);
            yi = __hfma2(w11.h[q], zC[3][q+4], yi);
            yR = __hfma2(w00.h[q], zR[RR][q],     yR);
            yR = __hfma2(w01.h[q], zR[RR][q+4],   yR);
            yR = __hfma2(w10.h[q], zR[RR+1][q],   yR);
            yR = __hfma2(w11.h[q], zR[RR+1][q+4], yR);
        }
        float rc = __low2float(yr) + __high2float(yr);
        float ic = __low2float(yi) + __high2float(yi);
        float rr = __low2float(yR) + __high2float(yR);
        float s = (rc*rc + ic*ic) * Wc + rr*rr * Wr;
        const float2* pw2 = (const float2*)(pwT + (f*4 + N)*32);
#pragma unroll
        for (int k = 0; k < 16; ++k) {
            float2 t = pw2[k];
            outa[k].x = fmaf(t.x, s, outa[k].x);
            outa[k].y = fmaf(t.y, s, outa[k].y);
        }
    }
}

// single real harmonic (m=0), rows R,R+1; optional central conv fold (h0)
template<int R, int N, bool CENTRAL>
__device__ __forceinline__ void mixr(const h2 (&z)[4][8],
    const int4* __restrict__ wt2n, const int4* __restrict__ cw2,
    const float* __restrict__ cbp, const __half* __restrict__ ldsh, int baseb,
    const float* __restrict__ pwT, float2 (&outa)[16])
{
    const float W = 1.f / (float)(2*N + 1);
    h2 xc[8];
    if (CENTRAL) {
        const int4* pc = (const int4*)((const char*)ldsh + baseb + CDEL*POSB);
        I4H xc0, xc1; xc0.v = pc[0]; xc1.v = pc[1];
#pragma unroll
        for (int q = 0; q < 4; ++q) { xc[q] = xc0.h[q]; xc[q+4] = xc1.h[q]; }
    }
#pragma unroll 2
    for (int f = 0; f < 32; ++f) {
        I4H w00, w01, w10, w11;
        w00.v = wt2n[f*4+0]; w01.v = wt2n[f*4+1];
        w10.v = wt2n[f*4+2]; w11.v = wt2n[f*4+3];
        h2 yr = __float2half2_rn(0.f);
#pragma unroll
        for (int q = 0; q < 4; ++q) {
            yr = __hfma2(w00.h[q], z[R][q],     yr);
            yr = __hfma2(w01.h[q], z[R][q+4],   yr);
            yr = __hfma2(w10.h[q], z[R+1][q],   yr);
            yr = __hfma2(w11.h[q], z[R+1][q+4], yr);
        }
        float yrf = __low2float(yr) + __high2float(yr);
        if (CENTRAL) {
            I4H c0, c1; c0.v = cw2[f*2]; c1.v = cw2[f*2+1];
            h2 acc = __float2half2_rn(0.f);
#pragma unroll
            for (int q = 0; q < 4; ++q) {
                acc = __hfma2(c0.h[q], xc[q],   acc);
                acc = __hfma2(c1.h[q], xc[q+4], acc);
            }
            yrf += cbp[f] + __low2float(acc) + __high2float(acc);
        }
        float s = yrf*yrf * W;
        const float2* pw2 = (const float2*)(pwT + (f*4 + N)*32);
#pragma unroll
        for (int k = 0; k < 16; ++k) {
            float2 t = pw2[k];
            outa[k].x = fmaf(t.x, s, outa[k].x);
            outa[k].y = fmaf(t.y, s, outa[k].y);
        }
    }
}

__global__ __launch_bounds__(512) void ssh_main(
    const float* __restrict__ x, const float* __restrict__ cb,
    const char* __restrict__ wsb, float* __restrict__ out)
{
    __shared__ __align__(16) __half ldsh[NPOS * CPAD];   // 36864 B
    const int tid = threadIdx.x;
    const int x0 = blockIdx.x * TX, y0 = blockIdx.y * TY, z0 = blockIdx.z * TZ;

    // stage x -> f16 LDS, channel-fastest, 2 channels per write (b32)
    for (int i = tid; i < NPOS * 8; i += 512) {
        int cp = i / NPOS;
        int pos = i - cp * NPOS;
        int lx = pos % LXX; int t1 = pos / LXX;
        int ly = t1 % LYY;  int lz = t1 / LYY;
        int gx = x0 + lx - 2, gy = y0 + ly - 2, gz = z0 + lz - 2;
        h2 hv = __float2half2_rn(0.f);
        if ((unsigned)gx < 48u && (unsigned)gy < 48u && (unsigned)gz < 48u) {
            int gi = ((2*cp*48 + gz)*48 + gy)*48 + gx;
            hv = __floats2half2_rn(x[gi], x[gi + 48*48*48]);
        }
        *(h2*)(ldsh + pos*CPAD + 2*cp) = hv;
    }
    __syncthreads();

    const int hg  = tid >> 7;          // 0..3, wave-uniform (2 waves per group)
    const int vid = tid & 127;
    const int tx = vid & 7, ty = (vid >> 3) & 3, tz = vid >> 5;
    const int baseb = (tz*(LYY*LXX) + ty*LXX + tx) * POSB;

    const int4* __restrict__ atab = (const int4*)(wsb + ATAB2_B);
    const int*  __restrict__ ed   = (const int*)(wsb + ED_B);
    const int4* __restrict__ wt2  = (const int4*)(wsb + WT2_B);
    const int4* __restrict__ cw2  = (const int4*)(wsb + CW2_B);
    const float* __restrict__ pwT = (const float*)(wsb + PWT_B);
    const float* __restrict__ obase = (const float*)(wsb + OB_B);

    float2 outa[16];
#pragma unroll
    for (int k = 0; k < 16; ++k) outa[k] = make_float2(0.f, 0.f);

    h2 zA[4][8], zB[4][8];
    if (hg == 0) {
        // n=3: h13,h14 (complex pair)
        conv2c(ldsh, baseb, atab + 13*92, atab + 14*92, ed, zA, zB);
        mixc2<3>(zA, zB, wt2 + 3*128, pwT, outa);
    } else if (hg == 1) {
        // n=3: h15 (complex) + h12 (real); n=0: h0 + central
        conv1c(ldsh, baseb, atab + 15*92, ed, zA);
        conv2r(ldsh, baseb, atab + 12*92, atab + 0*92, ed, zB);
        mix_cr<0,3>(zA, zB, wt2 + 3*128, pwT, outa);           // h15 + h12
        mixr<2,0,true>(zB, wt2 + 0*128, cw2, cb, ldsh, baseb, pwT, outa);  // h0
    } else if (hg == 2) {
        // n=2: h7,h8 (complex pair)
        conv2c(ldsh, baseb, atab + 7*92, atab + 8*92, ed, zA, zB);
        mixc2<2>(zA, zB, wt2 + 2*128, pwT, outa);
    } else {
        // n=2: h6 (real); n=1: h3 (complex) + h2 (real)
        conv2r(ldsh, baseb, atab + 6*92, atab + 2*92, ed, zA);
        conv1c(ldsh, baseb, atab + 3*92, ed, zB);
        mix_cr<2,1>(zB, zA, wt2 + 1*128, pwT, outa);           // h3 + h2
        mixr<0,2,false>(zA, wt2 + 2*128, cw2, cb, ldsh, baseb, pwT, outa); // h6
    }

    // ---- 2-stage merge through dead x-tile LDS (f32, stride 33) ----
    // region0: [0, 4224) f32  region1: [4224, 8448) f32   (8448*4 = 33792 <= 36864)
    __syncthreads();
    float* lmerge = (float*)ldsh;
    if (hg == 1) {
#pragma unroll
        for (int k = 0; k < 16; ++k) {
            lmerge[vid*33 + 2*k]     = outa[k].x;
            lmerge[vid*33 + 2*k + 1] = outa[k].y;
        }
    } else if (hg == 3) {
#pragma unroll
        for (int k = 0; k < 16; ++k) {
            lmerge[4224 + vid*33 + 2*k]     = outa[k].x;
            lmerge[4224 + vid*33 + 2*k + 1] = outa[k].y;
        }
    }
    __syncthreads();
    if (hg == 0) {
#pragma unroll
        for (int k = 0; k < 16; ++k) {
            outa[k].x += lmerge[vid*33 + 2*k];
            outa[k].y += lmerge[vid*33 + 2*k + 1];
        }
    } else if (hg == 2) {
        // read region1, accumulate, write back to region1 (self rmw, no race)
#pragma unroll
        for (int k = 0; k < 16; ++k) {
            outa[k].x += lmerge[4224 + vid*33 + 2*k];
            outa[k].y += lmerge[4224 + vid*33 + 2*k + 1];
        }
#pragma unroll
        for (int k = 0; k < 16; ++k) {
            lmerge[4224 + vid*33 + 2*k]     = outa[k].x;
            lmerge[4224 + vid*33 + 2*k + 1] = outa[k].y;
        }
    }
    __syncthreads();
    if (hg == 0) {
        const int gz = z0 + tz, gy = y0 + ty, gx = x0 + tx;
#pragma unroll
        for (int k = 0; k < 16; ++k) {
            float v0 = obase[2*k]   + outa[k].x + lmerge[4224 + vid*33 + 2*k];
            float v1 = obase[2*k+1] + outa[k].y + lmerge[4224 + vid*33 + 2*k + 1];
            out[(((2*k)*48   + gz)*48 + gy)*48 + gx] = fmaxf(v0, 0.f);
            out[(((2*k+1)*48 + gz)*48 + gy)*48 + gx] = fmaxf(v1, 0.f);
        }
    }
}

extern "C" void kernel_launch(void* const* d_in, const int* in_sizes, int n_in,
                              void* d_out, int out_size, void* d_ws, size_t ws_size,
                              hipStream_t stream) {
    const float* x  = (const float*)d_in[0];
    const float* w  = (const float*)d_in[1];
    const float* cw = (const float*)d_in[2];
    const float* cb = (const float*)d_in[3];
    const float* sb = (const float*)d_in[4];
    const float* pw = (const float*)d_in[5];
    const float* pb = (const float*)d_in[6];
    float* out = (float*)d_out;
    char* wsb = (char*)d_ws;

    ssh_init<<<dim3(1), dim3(256), 0, stream>>>(w, cw, pw, sb, pb, wsb);
    ssh_main<<<dim3(48/TX, 48/TY, 48/TZ), dim3(512), 0, stream>>>(x, cb, wsb, out);
}